// Round 5
// baseline (167.450 us; speedup 1.0000x reference)
//
#include <hip/hip_runtime.h>
#include <cmath>

#define BB 512
#define VV 128
#define DD 256
#define HH 4
#define DHH 64

typedef unsigned short u16;
typedef __attribute__((ext_vector_type(8))) short bf16x8;
typedef __attribute__((ext_vector_type(4))) short bf16x4;
typedef __attribute__((ext_vector_type(4))) float f32x4;

__device__ __forceinline__ u16 f2bf(float f) {
    unsigned u = __builtin_bit_cast(unsigned, f);
    u = (u + 0x7fffu + ((u >> 16) & 1u)) >> 16;
    return (u16)u;
}
__device__ __forceinline__ unsigned pk2(float a, float b) {
    return (unsigned)f2bf(a) | ((unsigned)f2bf(b) << 16);
}

// ---------------- K1: efmT[h][j][i] = adj[i,j] ? ea[i,j,:].Ew[h,:] : -inf ----
// Transposed layout so k_fused's P-compute reads 8 consecutive i per thread.
__global__ __launch_bounds__(256) void k_ef(const float* __restrict__ ea,
                                            const float* __restrict__ Ew,
                                            const int* __restrict__ adj,
                                            float* __restrict__ efmT) {
    __shared__ float tile[128 * 33];
    const int t = threadIdx.x;
    const int h = blockIdx.x, jt = blockIdx.y;
    const int tj = t & 31, ti = t >> 5;          // 32 j x 8 i threads
    const float e0 = Ew[h * 2], e1 = Ew[h * 2 + 1];
    for (int k = 0; k < 16; ++k) {
        int i  = k * 8 + ti;
        int ij = i * VV + jt * 32 + tj;
        float v = -INFINITY;
        if (adj[ij]) v = fmaf(ea[ij * 2 + 1], e1, ea[ij * 2] * e0);
        tile[i * 33 + tj] = v;
    }
    __syncthreads();
    const int i2 = t & 127, jh = t >> 7;
    float* dst = efmT + (size_t)h * VV * VV;
    for (int m = 0; m < 16; ++m) {
        int j = m * 2 + jh;                      // local j 0..31
        dst[(size_t)(jt * 32 + j) * VV + i2] = tile[i2 * 33 + j];
    }
}

// ---------------- K2: fully fused GAT per (b, head-pair) ----------------
// GEMM (128x128, K=256, bf16 MFMA, 4 waves 2x2) -> WxL[c][v] in LDS (union
// with As/Bs) + fused masked scores. Attention: P computed straight into
// MFMA A-fragments in registers (no LDS alT, no P barriers); denom via
// shfl_xor; 1/denom applied in C-layout epilogue via rden LDS; ELU; store.
__global__ __launch_bounds__(256, 4) void k_fused(
    const float* __restrict__ x, const float* __restrict__ Wm,
    const float* __restrict__ a, const float* __restrict__ efmT,
    const int* __restrict__ mask, float* __restrict__ out) {
    __shared__ u16 ubuf[128 * 136];     // GEMM: As+Bs (20.5KB); attn: WxL 34.8KB
    __shared__ float ssl[256], sdl[256], rden[2][128];
    __shared__ int mkl[128];

    u16* As  = ubuf;                    // [128][40]
    u16* Bs  = ubuf + 128 * 40;        // [128][40]
    u16* WxL = ubuf;                    // [c][v] stride 136 (post-GEMM)

    const int t = threadIdx.x;
    const int b = blockIdx.x, hp = blockIdx.y;
    const int w = t >> 6, L = t & 63;
    const int wr = w >> 1, wc = w & 1;
    const int lr = L & 15, lg = L >> 4;

    if (t < 128) mkl[t] = mask[b * VV + t];

    // ---- GEMM phase ----
    const int row = t >> 1, seg = t & 1;
    const float* xs = x  + ((size_t)b * VV + row) * DD + seg * 16;
    const float* ws = Wm + ((size_t)(hp * 128 + row)) * DD + seg * 16;
    u16* adst = As + row * 40 + seg * 16;
    u16* bdst = Bs + row * 40 + seg * 16;

    f32x4 acc[4][4];
    #pragma unroll
    for (int i = 0; i < 4; ++i)
        #pragma unroll
        for (int j = 0; j < 4; ++j) acc[i][j] = (f32x4){0.f, 0.f, 0.f, 0.f};

    float4 px[4], pw[4];
    #pragma unroll
    for (int q = 0; q < 4; ++q) {
        px[q] = *(const float4*)(xs + q * 4);
        pw[q] = *(const float4*)(ws + q * 4);
    }

    for (int ks = 0; ks < 8; ++ks) {
        bf16x8 va, vb, qa, qb;
        unsigned* vap = (unsigned*)&va; unsigned* vbp = (unsigned*)&vb;
        unsigned* qap = (unsigned*)&qa; unsigned* qbp = (unsigned*)&qb;
        vap[0] = pk2(px[0].x, px[0].y); vap[1] = pk2(px[0].z, px[0].w);
        vap[2] = pk2(px[1].x, px[1].y); vap[3] = pk2(px[1].z, px[1].w);
        vbp[0] = pk2(px[2].x, px[2].y); vbp[1] = pk2(px[2].z, px[2].w);
        vbp[2] = pk2(px[3].x, px[3].y); vbp[3] = pk2(px[3].z, px[3].w);
        qap[0] = pk2(pw[0].x, pw[0].y); qap[1] = pk2(pw[0].z, pw[0].w);
        qap[2] = pk2(pw[1].x, pw[1].y); qap[3] = pk2(pw[1].z, pw[1].w);
        qbp[0] = pk2(pw[2].x, pw[2].y); qbp[1] = pk2(pw[2].z, pw[2].w);
        qbp[2] = pk2(pw[3].x, pw[3].y); qbp[3] = pk2(pw[3].z, pw[3].w);
        *(bf16x8*)adst       = va;
        *(bf16x8*)(adst + 8) = vb;
        *(bf16x8*)bdst       = qa;
        *(bf16x8*)(bdst + 8) = qb;
        __syncthreads();
        if (ks < 7) {   // prefetch next K-tile; overlaps the MFMAs below
            #pragma unroll
            for (int q = 0; q < 4; ++q) {
                px[q] = *(const float4*)(xs + (ks + 1) * 32 + q * 4);
                pw[q] = *(const float4*)(ws + (ks + 1) * 32 + q * 4);
            }
        }
        bf16x8 af[4], bfr[4];
        #pragma unroll
        for (int mi = 0; mi < 4; ++mi)
            af[mi] = *(const bf16x8*)&As[(wr * 64 + mi * 16 + lr) * 40 + lg * 8];
        #pragma unroll
        for (int ni = 0; ni < 4; ++ni)
            bfr[ni] = *(const bf16x8*)&Bs[(wc * 64 + ni * 16 + lr) * 40 + lg * 8];
        #pragma unroll
        for (int mi = 0; mi < 4; ++mi)
            #pragma unroll
            for (int ni = 0; ni < 4; ++ni)
                acc[mi][ni] = __builtin_amdgcn_mfma_f32_16x16x32_bf16(
                    af[mi], bfr[ni], acc[mi][ni], 0, 0, 0);
        __syncthreads();   // after this in the last iter, As/Bs are dead
    }

    // ---- GEMM epilogue: WxL[c][v] bf16 (union over As/Bs) + masked scores ----
    float as_[4], ad_[4];
    #pragma unroll
    for (int ni = 0; ni < 4; ++ni) {
        as_[ni] = a[ni * 16 + lr];
        ad_[ni] = a[64 + ni * 16 + lr];
    }
    float ps[16], pd[16];
    #pragma unroll
    for (int k = 0; k < 16; ++k) { ps[k] = 0.f; pd[k] = 0.f; }
    #pragma unroll
    for (int mi = 0; mi < 4; ++mi) {
        #pragma unroll
        for (int ni = 0; ni < 4; ++ni) {
            const int c  = wc * 64 + ni * 16 + lr;    // hl*64 + d
            const int vb = wr * 64 + mi * 16 + lg * 4;
            bf16x4 o;
            #pragma unroll
            for (int r = 0; r < 4; ++r) {
                float v = acc[mi][ni][r];
                o[r] = (short)f2bf(v);
                ps[mi * 4 + r] = fmaf(v, as_[ni], ps[mi * 4 + r]);
                pd[mi * 4 + r] = fmaf(v, ad_[ni], pd[mi * 4 + r]);
            }
            *(bf16x4*)&WxL[c * 136 + vb] = o;
        }
    }
    #pragma unroll
    for (int k = 0; k < 16; ++k) {
        #pragma unroll
        for (int m = 1; m < 16; m <<= 1) {
            ps[k] += __shfl_xor(ps[k], m);
            pd[k] += __shfl_xor(pd[k], m);
        }
    }
    if (lr == 0) {
        #pragma unroll
        for (int mi = 0; mi < 4; ++mi)
            #pragma unroll
            for (int r = 0; r < 4; ++r) {
                int v = wr * 64 + mi * 16 + lg * 4 + r;
                bool mk = mkl[v] != 0;
                ssl[wc * 128 + v] = mk ? -INFINITY : ps[mi * 4 + r];
                sdl[wc * 128 + v] = mk ? -INFINITY : pd[mi * 4 + r];
            }
    }
    __syncthreads();   // WxL + scores ready

    // ---- Attention: P straight into A-fragments, per head ----
    const int j0 = w * 32 + lr;          // mi=0 row; mi=1 row = j0+16
    for (int hl = 0; hl < 2; ++hl) {
        const int h = hp * 2 + hl;
        const float sdj0 = sdl[hl * 128 + j0];
        const float sdj1 = sdl[hl * 128 + j0 + 16];
        const float* ef0 = efmT + ((size_t)h * VV + j0) * VV;
        const float* ef1 = ef0 + 16 * VV;
        bf16x8 af2[2][4];
        float ps0 = 0.f, ps1 = 0.f;
        #pragma unroll
        for (int ks = 0; ks < 4; ++ks) {
            const int i0 = ks * 32 + lg * 8;
            float sv[8], ev0[8], ev1[8];
            *(float4*)&sv[0]  = *(const float4*)&ssl[hl * 128 + i0];
            *(float4*)&sv[4]  = *(const float4*)&ssl[hl * 128 + i0 + 4];
            *(float4*)&ev0[0] = *(const float4*)(ef0 + i0);
            *(float4*)&ev0[4] = *(const float4*)(ef0 + i0 + 4);
            *(float4*)&ev1[0] = *(const float4*)(ef1 + i0);
            *(float4*)&ev1[4] = *(const float4*)(ef1 + i0 + 4);
            float p0[8], p1[8];
            #pragma unroll
            for (int u = 0; u < 8; ++u) {
                float e0 = sv[u] + sdj0 + ev0[u];
                float e1 = sv[u] + sdj1 + ev1[u];
                e0 = fmaxf(e0, 0.2f * e0);     // leaky relu
                e1 = fmaxf(e1, 0.2f * e1);
                p0[u] = __expf(e0); ps0 += p0[u];   // exp(-inf)=0 masks
                p1[u] = __expf(e1); ps1 += p1[u];
            }
            unsigned* a0 = (unsigned*)&af2[0][ks];
            unsigned* a1 = (unsigned*)&af2[1][ks];
            a0[0] = pk2(p0[0], p0[1]); a0[1] = pk2(p0[2], p0[3]);
            a0[2] = pk2(p0[4], p0[5]); a0[3] = pk2(p0[6], p0[7]);
            a1[0] = pk2(p1[0], p1[1]); a1[1] = pk2(p1[2], p1[3]);
            a1[2] = pk2(p1[4], p1[5]); a1[3] = pk2(p1[6], p1[7]);
        }
        // denom over all 128 i: lanes sharing j differ only in lg (bits 4,5)
        ps0 += __shfl_xor(ps0, 16); ps0 += __shfl_xor(ps0, 32);
        ps1 += __shfl_xor(ps1, 16); ps1 += __shfl_xor(ps1, 32);
        if (lg == 0) {
            rden[hl][j0]      = ps0 > 0.f ? 1.f / ps0 : 0.f;
            rden[hl][j0 + 16] = ps1 > 0.f ? 1.f / ps1 : 0.f;
        }

        f32x4 acc2[2][4];
        #pragma unroll
        for (int mi = 0; mi < 2; ++mi)
            #pragma unroll
            for (int ni = 0; ni < 4; ++ni) acc2[mi][ni] = (f32x4){0.f, 0.f, 0.f, 0.f};
        #pragma unroll
        for (int ks = 0; ks < 4; ++ks) {
            const int kk = ks * 32 + lg * 8;
            #pragma unroll
            for (int ni = 0; ni < 4; ++ni) {
                bf16x8 bf2 = *(const bf16x8*)&WxL[(hl * 64 + ni * 16 + lr) * 136 + kk];
                acc2[0][ni] = __builtin_amdgcn_mfma_f32_16x16x32_bf16(
                    af2[0][ks], bf2, acc2[0][ni], 0, 0, 0);
                acc2[1][ni] = __builtin_amdgcn_mfma_f32_16x16x32_bf16(
                    af2[1][ks], bf2, acc2[1][ni], 0, 0, 0);
            }
        }
        __syncthreads();   // rden[hl] visible to all; WxL stays read-only

        #pragma unroll
        for (int mi = 0; mi < 2; ++mi)
            #pragma unroll
            for (int ni = 0; ni < 4; ++ni) {
                const int dcol = ni * 16 + lr;
                const int jb   = w * 32 + mi * 16 + lg * 4;
                float* op = out + ((size_t)b * VV + jb) * DD + h * DHH + dcol;
                #pragma unroll
                for (int r = 0; r < 4; ++r) {
                    float v = acc2[mi][ni][r] * rden[hl][jb + r];
                    v = v > 0.f ? v : expm1f(v);   // ELU; masked/empty j -> 0
                    op[(size_t)r * DD] = v;
                }
            }
    }
}

extern "C" void kernel_launch(void* const* d_in, const int* in_sizes, int n_in,
                              void* d_out, int out_size, void* d_ws, size_t ws_size,
                              hipStream_t stream) {
    const float* x    = (const float*)d_in[0];
    const int*   adj  = (const int*)d_in[1];
    const float* ea   = (const float*)d_in[2];
    const int*   mask = (const int*)d_in[3];
    const float* Wm   = (const float*)d_in[4];
    const float* a    = (const float*)d_in[5];
    const float* Ew   = (const float*)d_in[6];
    float* out = (float*)d_out;

    float* efmT = (float*)d_ws;   // [H][j][i] fp32, 256 KiB

    k_ef<<<dim3(HH, VV / 32), 256, 0, stream>>>(ea, Ew, adj, efmT);
    k_fused<<<dim3(BB, 2), 256, 0, stream>>>(x, Wm, a, efmT, mask, out);
}

// Round 6
// 165.188 us; speedup vs baseline: 1.0137x; 1.0137x over previous
//
#include <hip/hip_runtime.h>
#include <hip/hip_bf16.h>
#include <cmath>

#define BB 512
#define VV 128
#define DD 256
#define HH 4
#define DHH 64

typedef unsigned short u16;
typedef __attribute__((ext_vector_type(8))) short bf16x8;
typedef __attribute__((ext_vector_type(4))) short bf16x4;
typedef __attribute__((ext_vector_type(4))) float f32x4;

// gfx950 hardware packed fp32->bf16 (v_cvt_pk_bf16_f32), RNE — one inst
// instead of ~8 VALU ops/scalar of the software round-and-shift sequence.
__device__ __forceinline__ unsigned pk2(float a, float b) {
    __hip_bfloat162 h = __float22bfloat162_rn(make_float2(a, b));
    unsigned r;
    __builtin_memcpy(&r, &h, sizeof(r));
    return r;
}

// ---------------- K1: efmT[h][j][i] = adj[i,j] ? ea[i,j,:].Ew[h,:] : -inf ----
// Transposed layout so k_fused's P-compute reads 8 consecutive i per thread.
__global__ __launch_bounds__(256) void k_ef(const float* __restrict__ ea,
                                            const float* __restrict__ Ew,
                                            const int* __restrict__ adj,
                                            float* __restrict__ efmT) {
    __shared__ float tile[128 * 33];
    const int t = threadIdx.x;
    const int h = blockIdx.x, jt = blockIdx.y;
    const int tj = t & 31, ti = t >> 5;          // 32 j x 8 i threads
    const float e0 = Ew[h * 2], e1 = Ew[h * 2 + 1];
    for (int k = 0; k < 16; ++k) {
        int i  = k * 8 + ti;
        int ij = i * VV + jt * 32 + tj;
        float v = -INFINITY;
        if (adj[ij]) v = fmaf(ea[ij * 2 + 1], e1, ea[ij * 2] * e0);
        tile[i * 33 + tj] = v;
    }
    __syncthreads();
    const int i2 = t & 127, jh = t >> 7;
    float* dst = efmT + (size_t)h * VV * VV;
    for (int m = 0; m < 16; ++m) {
        int j = m * 2 + jh;                      // local j 0..31
        dst[(size_t)(jt * 32 + j) * VV + i2] = tile[i2 * 33 + j];
    }
}

// ---------------- K2: fully fused GAT per (b, head-pair) ----------------
// GEMM (128x128, K=256, bf16 MFMA, 4 waves 2x2) -> WxL[c][v] in LDS (union
// with As/Bs) + fused masked scores. Attention: P computed straight into
// MFMA A-fragments in registers (no LDS alT); denom via shfl_xor; 1/denom
// applied in C-layout epilogue via rden LDS; ELU; store.
__global__ __launch_bounds__(256, 4) void k_fused(
    const float* __restrict__ x, const float* __restrict__ Wm,
    const float* __restrict__ a, const float* __restrict__ efmT,
    const int* __restrict__ mask, float* __restrict__ out) {
    __shared__ u16 ubuf[128 * 136];     // GEMM: As+Bs (20.5KB); attn: WxL 34.8KB
    __shared__ float ssl[256], sdl[256], rden[2][128];
    __shared__ int mkl[128];

    u16* As  = ubuf;                    // [128][40]
    u16* Bs  = ubuf + 128 * 40;        // [128][40]
    u16* WxL = ubuf;                    // [c][v] stride 136 (post-GEMM)

    const int t = threadIdx.x;
    const int b = blockIdx.x, hp = blockIdx.y;
    const int w = t >> 6, L = t & 63;
    const int wr = w >> 1, wc = w & 1;
    const int lr = L & 15, lg = L >> 4;

    if (t < 128) mkl[t] = mask[b * VV + t];

    // ---- GEMM phase ----
    const int row = t >> 1, seg = t & 1;
    const float* xs = x  + ((size_t)b * VV + row) * DD + seg * 16;
    const float* ws = Wm + ((size_t)(hp * 128 + row)) * DD + seg * 16;
    u16* adst = As + row * 40 + seg * 16;
    u16* bdst = Bs + row * 40 + seg * 16;

    f32x4 acc[4][4];
    #pragma unroll
    for (int i = 0; i < 4; ++i)
        #pragma unroll
        for (int j = 0; j < 4; ++j) acc[i][j] = (f32x4){0.f, 0.f, 0.f, 0.f};

    float4 px[4], pw[4];
    #pragma unroll
    for (int q = 0; q < 4; ++q) {
        px[q] = *(const float4*)(xs + q * 4);
        pw[q] = *(const float4*)(ws + q * 4);
    }

    for (int ks = 0; ks < 8; ++ks) {
        unsigned va[4], vb[4], qa[4], qb[4];
        va[0] = pk2(px[0].x, px[0].y); va[1] = pk2(px[0].z, px[0].w);
        va[2] = pk2(px[1].x, px[1].y); va[3] = pk2(px[1].z, px[1].w);
        vb[0] = pk2(px[2].x, px[2].y); vb[1] = pk2(px[2].z, px[2].w);
        vb[2] = pk2(px[3].x, px[3].y); vb[3] = pk2(px[3].z, px[3].w);
        qa[0] = pk2(pw[0].x, pw[0].y); qa[1] = pk2(pw[0].z, pw[0].w);
        qa[2] = pk2(pw[1].x, pw[1].y); qa[3] = pk2(pw[1].z, pw[1].w);
        qb[0] = pk2(pw[2].x, pw[2].y); qb[1] = pk2(pw[2].z, pw[2].w);
        qb[2] = pk2(pw[3].x, pw[3].y); qb[3] = pk2(pw[3].z, pw[3].w);
        *(bf16x8*)adst       = *(bf16x8*)&va[0];
        *(bf16x8*)(adst + 8) = *(bf16x8*)&vb[0];
        *(bf16x8*)bdst       = *(bf16x8*)&qa[0];
        *(bf16x8*)(bdst + 8) = *(bf16x8*)&qb[0];
        __syncthreads();
        if (ks < 7) {   // prefetch next K-tile; overlaps the MFMAs below
            #pragma unroll
            for (int q = 0; q < 4; ++q) {
                px[q] = *(const float4*)(xs + (ks + 1) * 32 + q * 4);
                pw[q] = *(const float4*)(ws + (ks + 1) * 32 + q * 4);
            }
        }
        bf16x8 af[4], bfr[4];
        #pragma unroll
        for (int mi = 0; mi < 4; ++mi)
            af[mi] = *(const bf16x8*)&As[(wr * 64 + mi * 16 + lr) * 40 + lg * 8];
        #pragma unroll
        for (int ni = 0; ni < 4; ++ni)
            bfr[ni] = *(const bf16x8*)&Bs[(wc * 64 + ni * 16 + lr) * 40 + lg * 8];
        #pragma unroll
        for (int mi = 0; mi < 4; ++mi)
            #pragma unroll
            for (int ni = 0; ni < 4; ++ni)
                acc[mi][ni] = __builtin_amdgcn_mfma_f32_16x16x32_bf16(
                    af[mi], bfr[ni], acc[mi][ni], 0, 0, 0);
        __syncthreads();   // after this in the last iter, As/Bs are dead
    }

    // ---- GEMM epilogue: WxL[c][v] bf16 (union over As/Bs) + masked scores ----
    float as_[4], ad_[4];
    #pragma unroll
    for (int ni = 0; ni < 4; ++ni) {
        as_[ni] = a[ni * 16 + lr];
        ad_[ni] = a[64 + ni * 16 + lr];
    }
    float ps[16], pd[16];
    #pragma unroll
    for (int k = 0; k < 16; ++k) { ps[k] = 0.f; pd[k] = 0.f; }
    #pragma unroll
    for (int mi = 0; mi < 4; ++mi) {
        #pragma unroll
        for (int ni = 0; ni < 4; ++ni) {
            const int c  = wc * 64 + ni * 16 + lr;    // hl*64 + d
            const int vb = wr * 64 + mi * 16 + lg * 4;
            unsigned o2[2];
            o2[0] = pk2(acc[mi][ni][0], acc[mi][ni][1]);
            o2[1] = pk2(acc[mi][ni][2], acc[mi][ni][3]);
            #pragma unroll
            for (int r = 0; r < 4; ++r) {
                float v = acc[mi][ni][r];
                ps[mi * 4 + r] = fmaf(v, as_[ni], ps[mi * 4 + r]);
                pd[mi * 4 + r] = fmaf(v, ad_[ni], pd[mi * 4 + r]);
            }
            *(uint2*)&WxL[c * 136 + vb] = *(uint2*)&o2[0];   // ds_write_b64
        }
    }
    #pragma unroll
    for (int k = 0; k < 16; ++k) {
        #pragma unroll
        for (int m = 1; m < 16; m <<= 1) {
            ps[k] += __shfl_xor(ps[k], m);
            pd[k] += __shfl_xor(pd[k], m);
        }
    }
    if (lr == 0) {
        #pragma unroll
        for (int mi = 0; mi < 4; ++mi)
            #pragma unroll
            for (int r = 0; r < 4; ++r) {
                int v = wr * 64 + mi * 16 + lg * 4 + r;
                bool mk = mkl[v] != 0;
                ssl[wc * 128 + v] = mk ? -INFINITY : ps[mi * 4 + r];
                sdl[wc * 128 + v] = mk ? -INFINITY : pd[mi * 4 + r];
            }
    }
    __syncthreads();   // WxL + scores ready

    // ---- Attention: P straight into A-fragments, per head ----
    const int j0 = w * 32 + lr;          // mi=0 row; mi=1 row = j0+16
    for (int hl = 0; hl < 2; ++hl) {
        const int h = hp * 2 + hl;
        const float sdj0 = sdl[hl * 128 + j0];
        const float sdj1 = sdl[hl * 128 + j0 + 16];
        const float* ef0 = efmT + ((size_t)h * VV + j0) * VV;
        const float* ef1 = ef0 + 16 * VV;
        bf16x8 af2[2][4];
        float ps0 = 0.f, ps1 = 0.f;
        #pragma unroll
        for (int ks = 0; ks < 4; ++ks) {
            const int i0 = ks * 32 + lg * 8;
            float sv[8], ev0[8], ev1[8];
            *(float4*)&sv[0]  = *(const float4*)&ssl[hl * 128 + i0];
            *(float4*)&sv[4]  = *(const float4*)&ssl[hl * 128 + i0 + 4];
            *(float4*)&ev0[0] = *(const float4*)(ef0 + i0);
            *(float4*)&ev0[4] = *(const float4*)(ef0 + i0 + 4);
            *(float4*)&ev1[0] = *(const float4*)(ef1 + i0);
            *(float4*)&ev1[4] = *(const float4*)(ef1 + i0 + 4);
            float p0[8], p1[8];
            #pragma unroll
            for (int u = 0; u < 8; ++u) {
                float e0 = sv[u] + sdj0 + ev0[u];
                float e1 = sv[u] + sdj1 + ev1[u];
                e0 = fmaxf(e0, 0.2f * e0);     // leaky relu
                e1 = fmaxf(e1, 0.2f * e1);
                p0[u] = __expf(e0); ps0 += p0[u];   // exp(-inf)=0 masks
                p1[u] = __expf(e1); ps1 += p1[u];
            }
            unsigned* a0 = (unsigned*)&af2[0][ks];
            unsigned* a1 = (unsigned*)&af2[1][ks];
            a0[0] = pk2(p0[0], p0[1]); a0[1] = pk2(p0[2], p0[3]);
            a0[2] = pk2(p0[4], p0[5]); a0[3] = pk2(p0[6], p0[7]);
            a1[0] = pk2(p1[0], p1[1]); a1[1] = pk2(p1[2], p1[3]);
            a1[2] = pk2(p1[4], p1[5]); a1[3] = pk2(p1[6], p1[7]);
        }
        // denom over all 128 i: lanes sharing j differ only in lg (bits 4,5)
        ps0 += __shfl_xor(ps0, 16); ps0 += __shfl_xor(ps0, 32);
        ps1 += __shfl_xor(ps1, 16); ps1 += __shfl_xor(ps1, 32);
        if (lg == 0) {
            rden[hl][j0]      = ps0 > 0.f ? 1.f / ps0 : 0.f;
            rden[hl][j0 + 16] = ps1 > 0.f ? 1.f / ps1 : 0.f;
        }

        f32x4 acc2[2][4];
        #pragma unroll
        for (int mi = 0; mi < 2; ++mi)
            #pragma unroll
            for (int ni = 0; ni < 4; ++ni) acc2[mi][ni] = (f32x4){0.f, 0.f, 0.f, 0.f};
        #pragma unroll
        for (int ks = 0; ks < 4; ++ks) {
            const int kk = ks * 32 + lg * 8;
            #pragma unroll
            for (int ni = 0; ni < 4; ++ni) {
                bf16x8 bf2 = *(const bf16x8*)&WxL[(hl * 64 + ni * 16 + lr) * 136 + kk];
                acc2[0][ni] = __builtin_amdgcn_mfma_f32_16x16x32_bf16(
                    af2[0][ks], bf2, acc2[0][ni], 0, 0, 0);
                acc2[1][ni] = __builtin_amdgcn_mfma_f32_16x16x32_bf16(
                    af2[1][ks], bf2, acc2[1][ni], 0, 0, 0);
            }
        }
        __syncthreads();   // rden[hl] visible to all; WxL stays read-only

        #pragma unroll
        for (int mi = 0; mi < 2; ++mi)
            #pragma unroll
            for (int ni = 0; ni < 4; ++ni) {
                const int dcol = ni * 16 + lr;
                const int jb   = w * 32 + mi * 16 + lg * 4;
                float* op = out + ((size_t)b * VV + jb) * DD + h * DHH + dcol;
                #pragma unroll
                for (int r = 0; r < 4; ++r) {
                    float v = acc2[mi][ni][r] * rden[hl][jb + r];
                    v = v > 0.f ? v : expm1f(v);   // ELU; masked/empty j -> 0
                    op[(size_t)r * DD] = v;
                }
            }
    }
}

extern "C" void kernel_launch(void* const* d_in, const int* in_sizes, int n_in,
                              void* d_out, int out_size, void* d_ws, size_t ws_size,
                              hipStream_t stream) {
    const float* x    = (const float*)d_in[0];
    const int*   adj  = (const int*)d_in[1];
    const float* ea   = (const float*)d_in[2];
    const int*   mask = (const int*)d_in[3];
    const float* Wm   = (const float*)d_in[4];
    const float* a    = (const float*)d_in[5];
    const float* Ew   = (const float*)d_in[6];
    float* out = (float*)d_out;

    float* efmT = (float*)d_ws;   // [H][j][i] fp32, 256 KiB

    k_ef<<<dim3(HH, VV / 32), 256, 0, stream>>>(ea, Ew, adj, efmT);
    k_fused<<<dim3(BB, 2), 256, 0, stream>>>(x, Wm, a, efmT, mask, out);
}